// Round 5
// baseline (1676.694 us; speedup 1.0000x reference)
//
#include <hip/hip_runtime.h>
#include <hip/hip_fp16.h>
#include <cstdint>
#include <cstddef>

// MoE FFN, D=512 F=2048 E=8 K=2, N=32768 tokens. fp16 MFMA.
// GEMMs: M=32 x N=512 tiles; B-fragments read DIRECTLY from global (L2-hot
// weights), depth-1 register ping-pong; only the 2 KB A-tile goes through LDS
// (depth-2 register prefetch, raw lgkm-only barrier so B loads stay in flight).
#define NTOK 32768
#define DM 512
#define FF 2048
#define NE 8

typedef _Float16 half8 __attribute__((ext_vector_type(8)));
typedef float floatx4 __attribute__((ext_vector_type(4)));

#define LGKM0_BARRIER() do { \
  asm volatile("s_waitcnt lgkmcnt(0)" ::: "memory"); \
  __builtin_amdgcn_s_barrier(); \
} while (0)

__device__ __forceinline__ float gelu_tanh(float v) {
  // tanh-form GELU; |err| vs exact erf-GELU < ~3e-3, well under threshold.
  float u = v * 0.7978845608028654f * (1.f + 0.044715f * v * v);
  float ex = __expf(2.f * u);
  float t = 1.f - 2.f / (ex + 1.f);
  return 0.5f * v * (1.f + t);
}

// ---------------- transpose + fp32->fp16 cast: W (E,R,C) -> Wt (E,C,R) ----------------
__global__ __launch_bounds__(256) void k_transpose(const float* __restrict__ W,
                                                   _Float16* __restrict__ Wt, int R, int C) {
  __shared__ float tile[32][33];
  int e = blockIdx.z;
  int c0 = blockIdx.x * 32, r0 = blockIdx.y * 32;
  const float* Wp = W + (size_t)e * R * C;
  _Float16* Wtp = Wt + (size_t)e * R * C;
  int tx = threadIdx.x & 31, ty = threadIdx.x >> 5;
  #pragma unroll
  for (int rr = ty; rr < 32; rr += 8)
    tile[rr][tx] = Wp[(size_t)(r0 + rr) * C + c0 + tx];
  __syncthreads();
  #pragma unroll
  for (int cc = ty; cc < 32; cc += 8)
    Wtp[(size_t)(c0 + cc) * R + r0 + tx] = (_Float16)tile[tx][cc];
}

// ---------------- router: logits, top-2, softmax weights, aux accumulators, x->f16 ----------------
__global__ __launch_bounds__(256) void k_router(
    const float* __restrict__ x, const float* __restrict__ rw,
    _Float16* __restrict__ xb, int* __restrict__ route_e, float* __restrict__ route_w,
    int* __restrict__ counts, float* __restrict__ aux_acc) {
  __shared__ float s_p[NE];
  __shared__ float s_c[NE];
  __shared__ int s_cnt[NE];
  int tid = threadIdx.x, lane = tid & 63, wave = tid >> 6;
  if (tid < NE) { s_p[tid] = 0.f; s_c[tid] = 0.f; s_cnt[tid] = 0; }
  __syncthreads();
  int n = blockIdx.x * 4 + wave;  // one wave per token
  const float4* xr = (const float4*)(x + (size_t)n * DM + lane * 8);
  float4 x0 = xr[0], x1 = xr[1];
  float xv[8] = {x0.x, x0.y, x0.z, x0.w, x1.x, x1.y, x1.z, x1.w};
  float acc[NE];
  #pragma unroll
  for (int e = 0; e < NE; e++) acc[e] = 0.f;
  const float4* rwv = (const float4*)rw;  // (D, E=8) row-major: 2 float4 per row
  #pragma unroll
  for (int j = 0; j < 8; j++) {
    int d = lane * 8 + j;
    float4 r0 = rwv[d * 2], r1 = rwv[d * 2 + 1];
    float xd = xv[j];
    acc[0] += xd * r0.x; acc[1] += xd * r0.y; acc[2] += xd * r0.z; acc[3] += xd * r0.w;
    acc[4] += xd * r1.x; acc[5] += xd * r1.y; acc[6] += xd * r1.z; acc[7] += xd * r1.w;
  }
  half8 hv;
  #pragma unroll
  for (int j = 0; j < 8; j++) hv[j] = (_Float16)xv[j];
  *(half8*)(xb + (size_t)n * DM + lane * 8) = hv;
  #pragma unroll
  for (int e = 0; e < NE; e++) {
    #pragma unroll
    for (int m = 1; m < 64; m <<= 1) acc[e] += __shfl_xor(acc[e], m);
  }
  if (lane == 0) {
    int e0 = 0; float v0 = acc[0];
    for (int e = 1; e < NE; e++) if (acc[e] > v0) { v0 = acc[e]; e0 = e; }
    int e1 = (e0 == 0) ? 1 : 0; float v1 = acc[e1];
    for (int e = 0; e < NE; e++) if (e != e0 && acc[e] > v1) { v1 = acc[e]; e1 = e; }
    float w0 = 1.f / (1.f + expf(v1 - v0));
    float w1 = 1.f - w0;
    route_e[n] = e0 | (e1 << 8);
    route_w[2 * n] = w0; route_w[2 * n + 1] = w1;
    float mx = acc[0];
    for (int e = 1; e < NE; e++) mx = fmaxf(mx, acc[e]);
    float p[NE]; float s = 0.f;
    for (int e = 0; e < NE; e++) { p[e] = expf(acc[e] - mx); s += p[e]; }
    float inv = 1.f / s;
    atomicAdd(&s_cnt[e0], 1); atomicAdd(&s_cnt[e1], 1);
    for (int e = 0; e < NE; e++) atomicAdd(&s_p[e], p[e] * inv);
    atomicAdd(&s_c[e0], 1.f);
  }
  __syncthreads();
  if (tid < NE) {
    atomicAdd(&counts[tid], s_cnt[tid]);
    atomicAdd(&aux_acc[tid], s_p[tid]);
    atomicAdd(&aux_acc[NE + tid], s_c[tid]);
  }
}

// ---------------- offsets (prefix sum over 8) + aux loss ----------------
__global__ void k_finalize(const int* __restrict__ counts, int* __restrict__ offsets,
                           int* __restrict__ cursors, const float* __restrict__ aux_acc,
                           float* __restrict__ out_aux) {
  if (threadIdx.x == 0 && blockIdx.x == 0) {
    int off = 0;
    for (int e = 0; e < NE; e++) { offsets[e] = off; cursors[e] = off; off += counts[e]; }
    const float invN = 1.f / (float)NTOK;
    float aux = 0.f;
    for (int e = 0; e < NE; e++) aux += (aux_acc[e] * invN) * (aux_acc[NE + e] * invN);
    out_aux[0] = 0.01f * (float)NE * aux;
  }
}

// ---------------- build compacted per-expert token lists ----------------
__global__ __launch_bounds__(256) void k_build(
    const int* __restrict__ route_e, const float* __restrict__ route_w,
    int* __restrict__ cursors, int* __restrict__ tok, float* __restrict__ wgt) {
  __shared__ int s_cnt[NE];
  __shared__ int s_base[NE];
  int tid = threadIdx.x;
  if (tid < NE) s_cnt[tid] = 0;
  __syncthreads();
  int n = blockIdx.x * 256 + tid;
  int re = route_e[n];
  int e0 = re & 0xff, e1 = (re >> 8) & 0xff;
  float w0 = route_w[2 * n], w1 = route_w[2 * n + 1];
  int p0 = atomicAdd(&s_cnt[e0], 1);
  int p1 = atomicAdd(&s_cnt[e1], 1);
  __syncthreads();
  if (tid < NE) s_base[tid] = atomicAdd(&cursors[tid], s_cnt[tid]);
  __syncthreads();
  int g0 = s_base[e0] + p0, g1 = s_base[e1] + p1;
  tok[g0] = n; wgt[g0] = w0;
  tok[g1] = n; wgt[g1] = w1;
}

// ---------------- GEMM1: h[:, fbase+nb*512 .. +512] = gelu(Xg @ w1[e] + b1[e]) ----------------
// M=32 tokens, N=512 (4 waves x 128), K=DM. B-frags direct from global; A via 2-stage LDS.
__global__ __launch_bounds__(256, 2) void k_ffn1(
    const _Float16* __restrict__ xb, const _Float16* __restrict__ w1t,
    const float* __restrict__ b1, const int* __restrict__ counts,
    const int* __restrict__ offsets, const int* __restrict__ tok,
    _Float16* __restrict__ h, int Fc, int fbase) {
  int e = blockIdx.z;
  int cnt = counts[e];
  int tm = blockIdx.y;
  if (tm * 32 >= cnt) return;
  int nb = blockIdx.x;
  int off = offsets[e];
  __shared__ _Float16 As[2 * 1024];  // 2 stages x (32 rows x 32 k)
  int tid = threadIdx.x, lane = tid & 63, wave = tid >> 6;
  int fr = lane & 15, kf8 = (lane >> 4) * 8;

  // A staging: waves 0-1 (tid<128): row r = tid>>2, 8-half chunk (tid&3)*8
  const _Float16* ga = xb;
  int wa = 0;
  if (tid < 128) {
    int r = tid >> 2;
    int row = tm * 32 + r; if (row >= cnt) row = cnt - 1;
    ga = xb + (size_t)tok[off + row] * DM + (tid & 3) * 8;
    wa = r * 32 + (tid & 3) * 8;
  }
  // B pointers: 8 n-frags of 16 rows each (n = f index)
  const _Float16* w1e = w1t + (size_t)e * FF * DM;
  int nbase = fbase + nb * 512 + wave * 128;
  const _Float16* Bg[8];
  #pragma unroll
  for (int j = 0; j < 8; j++)
    Bg[j] = w1e + (size_t)(nbase + j * 16 + fr) * DM + kf8;

  floatx4 acc[2][8];
  floatx4 zero = {0.f, 0.f, 0.f, 0.f};
  #pragma unroll
  for (int m = 0; m < 2; m++)
    #pragma unroll
    for (int j = 0; j < 8; j++) acc[m][j] = zero;

  half8 bva[8], bvb[8];
  #pragma unroll
  for (int j = 0; j < 8; j++) bva[j] = *(const half8*)(Bg[j]);

  half8 ra;
  if (tid < 128) {
    ra = *(const half8*)(ga);
    *(half8*)(As + wa) = ra;
    ra = *(const half8*)(ga + 32);
  }
  LGKM0_BARRIER();

  const int niter = DM / 32;  // 16, even
  auto stageA = [&](int k) {
    if (tid < 128) {
      if (k + 1 < niter) *(half8*)(As + (((k + 1) & 1) * 1024) + wa) = ra;
      if (k + 2 < niter) ra = *(const half8*)(ga + (k + 2) * 32);
    }
  };
  auto domfma = [&](const half8* bv, int cur) {
    half8 av0 = *(const half8*)(As + cur + fr * 32 + kf8);
    half8 av1 = *(const half8*)(As + cur + (16 + fr) * 32 + kf8);
    #pragma unroll
    for (int j = 0; j < 8; j++) {
      acc[0][j] = __builtin_amdgcn_mfma_f32_16x16x32_f16(av0, bv[j], acc[0][j], 0, 0, 0);
      acc[1][j] = __builtin_amdgcn_mfma_f32_16x16x32_f16(av1, bv[j], acc[1][j], 0, 0, 0);
    }
  };
  for (int k = 0; k < niter; k += 2) {
    stageA(k);
    if (k + 1 < niter) {
      int k0 = (k + 1) * 32;
      #pragma unroll
      for (int j = 0; j < 8; j++) bvb[j] = *(const half8*)(Bg[j] + k0);
    }
    domfma(bva, 0);
    LGKM0_BARRIER();
    stageA(k + 1);
    if (k + 2 < niter) {
      int k0 = (k + 2) * 32;
      #pragma unroll
      for (int j = 0; j < 8; j++) bva[j] = *(const half8*)(Bg[j] + k0);
    }
    domfma(bvb, 1024);
    if (k + 2 < niter) LGKM0_BARRIER();
  }

  int rq = (lane >> 4) * 4, cq = lane & 15;
  #pragma unroll
  for (int j = 0; j < 8; j++) {
    int colL = nb * 512 + wave * 128 + j * 16 + cq;  // col within Fc chunk
    float bb = b1[e * FF + fbase + colL];
    #pragma unroll
    for (int mt = 0; mt < 2; mt++) {
      #pragma unroll
      for (int r = 0; r < 4; r++) {
        int row = tm * 32 + mt * 16 + rq + r;
        if (row < cnt) {
          float v = gelu_tanh(acc[mt][j][r] + bb);
          h[(size_t)(off + row) * Fc + colL] = (_Float16)v;
        }
      }
    }
  }
}

// ---------------- GEMM2: out[tok] += w * (Hc @ w2[e] slice (+ b2 on chunk 0)) ----------------
// M=32 slots, N=512=DM full width, K=Fc.
__global__ __launch_bounds__(256, 2) void k_ffn2(
    const _Float16* __restrict__ h, const _Float16* __restrict__ w2t,
    const float* __restrict__ b2, const int* __restrict__ counts,
    const int* __restrict__ offsets, const int* __restrict__ tok,
    const float* __restrict__ wgt, float* __restrict__ out, int Fc, int fbase) {
  int e = blockIdx.z;
  int cnt = counts[e];
  int tm = blockIdx.y;
  if (tm * 32 >= cnt) return;
  int off = offsets[e];
  __shared__ _Float16 As[2 * 1024];
  int tid = threadIdx.x, lane = tid & 63, wave = tid >> 6;
  int fr = lane & 15, kf8 = (lane >> 4) * 8;

  const _Float16* ga = h;
  int wa = 0;
  if (tid < 128) {
    int r = tid >> 2;
    int row = tm * 32 + r; if (row >= cnt) row = cnt - 1;
    ga = h + (size_t)(off + row) * Fc + (tid & 3) * 8;
    wa = r * 32 + (tid & 3) * 8;
  }
  const _Float16* w2e = w2t + (size_t)e * DM * FF;  // (D rows, F cols), k contiguous
  int nbase = wave * 128;
  const _Float16* Bg[8];
  #pragma unroll
  for (int j = 0; j < 8; j++)
    Bg[j] = w2e + (size_t)(nbase + j * 16 + fr) * FF + fbase + kf8;

  floatx4 acc[2][8];
  floatx4 zero = {0.f, 0.f, 0.f, 0.f};
  #pragma unroll
  for (int m = 0; m < 2; m++)
    #pragma unroll
    for (int j = 0; j < 8; j++) acc[m][j] = zero;

  half8 bva[8], bvb[8];
  #pragma unroll
  for (int j = 0; j < 8; j++) bva[j] = *(const half8*)(Bg[j]);

  half8 ra;
  if (tid < 128) {
    ra = *(const half8*)(ga);
    *(half8*)(As + wa) = ra;
    ra = *(const half8*)(ga + 32);
  }
  LGKM0_BARRIER();

  const int niter = Fc / 32;  // 16/32/64, even
  auto stageA = [&](int k) {
    if (tid < 128) {
      if (k + 1 < niter) *(half8*)(As + (((k + 1) & 1) * 1024) + wa) = ra;
      if (k + 2 < niter) ra = *(const half8*)(ga + (k + 2) * 32);
    }
  };
  auto domfma = [&](const half8* bv, int cur) {
    half8 av0 = *(const half8*)(As + cur + fr * 32 + kf8);
    half8 av1 = *(const half8*)(As + cur + (16 + fr) * 32 + kf8);
    #pragma unroll
    for (int j = 0; j < 8; j++) {
      acc[0][j] = __builtin_amdgcn_mfma_f32_16x16x32_f16(av0, bv[j], acc[0][j], 0, 0, 0);
      acc[1][j] = __builtin_amdgcn_mfma_f32_16x16x32_f16(av1, bv[j], acc[1][j], 0, 0, 0);
    }
  };
  for (int k = 0; k < niter; k += 2) {
    stageA(k);
    if (k + 1 < niter) {
      int k0 = (k + 1) * 32;
      #pragma unroll
      for (int j = 0; j < 8; j++) bvb[j] = *(const half8*)(Bg[j] + k0);
    }
    domfma(bva, 0);
    LGKM0_BARRIER();
    stageA(k + 1);
    if (k + 2 < niter) {
      int k0 = (k + 2) * 32;
      #pragma unroll
      for (int j = 0; j < 8; j++) bva[j] = *(const half8*)(Bg[j] + k0);
    }
    domfma(bvb, 1024);
    if (k + 2 < niter) LGKM0_BARRIER();
  }

  int rq = (lane >> 4) * 4, cq = lane & 15;
  int addb = (fbase == 0) ? 1 : 0;
  #pragma unroll
  for (int j = 0; j < 8; j++) {
    int col = wave * 128 + j * 16 + cq;
    float bb = addb ? b2[e * DM + col] : 0.f;
    #pragma unroll
    for (int mt = 0; mt < 2; mt++) {
      #pragma unroll
      for (int r = 0; r < 4; r++) {
        int row = tm * 32 + mt * 16 + rq + r;
        if (row < cnt) {
          int t = tok[off + row];
          float w = wgt[off + row];
          atomicAdd(&out[(size_t)t * DM + col], w * (acc[mt][j][r] + bb));
        }
      }
    }
  }
}

extern "C" void kernel_launch(void* const* d_in, const int* in_sizes, int n_in,
                              void* d_out, int out_size, void* d_ws, size_t ws_size,
                              hipStream_t stream) {
  const float* x  = (const float*)d_in[0];
  const float* rw = (const float*)d_in[1];
  const float* w1 = (const float*)d_in[2];
  const float* b1 = (const float*)d_in[3];
  const float* w2 = (const float*)d_in[4];
  const float* b2 = (const float*)d_in[5];
  float* out = (float*)d_out;

  uint8_t* ws = (uint8_t*)d_ws;
  _Float16* xb  = (_Float16*)ws;  ws += (size_t)NTOK * DM * 2;       // 33.5 MB
  _Float16* w1t = (_Float16*)ws;  ws += (size_t)NE * FF * DM * 2;    // 16.8 MB
  _Float16* w2t = (_Float16*)ws;  ws += (size_t)NE * DM * FF * 2;    // 16.8 MB
  int*   tok     = (int*)ws;      ws += (size_t)2 * NTOK * 4;
  float* wgt     = (float*)ws;    ws += (size_t)2 * NTOK * 4;
  int*   route_e = (int*)ws;      ws += (size_t)NTOK * 4;
  float* route_w = (float*)ws;    ws += (size_t)NTOK * 8;
  int*   counts  = (int*)ws;      ws += 8 * 4;
  int*   offsets = (int*)ws;      ws += 8 * 4;
  int*   cursors = (int*)ws;      ws += 8 * 4;
  float* aux     = (float*)ws;    ws += 16 * 4;
  _Float16* h   = (_Float16*)ws;  // K-chunked h buffer: 2*NTOK rows x Fc cols

  size_t fixed = (size_t)(ws - (uint8_t*)d_ws);
  int Fc = FF;  // largest F-chunk that fits the workspace (min 512 for 512-wide n-blocks)
  while (Fc > 512 && fixed + (size_t)2 * NTOK * (size_t)Fc * 2 > ws_size) Fc >>= 1;
  int NC = FF / Fc;

  hipMemsetAsync(d_out, 0, (size_t)out_size * 4, stream);           // scatter-add target
  hipMemsetAsync(counts, 0, (8 + 8 + 8 + 16) * 4, stream);          // counts..aux

  k_transpose<<<dim3(FF / 32, DM / 32, NE), 256, 0, stream>>>(w1, w1t, DM, FF);
  k_transpose<<<dim3(DM / 32, FF / 32, NE), 256, 0, stream>>>(w2, w2t, FF, DM);
  k_router<<<NTOK / 4, 256, 0, stream>>>(x, rw, xb, route_e, route_w, counts, aux);
  k_finalize<<<1, 64, 0, stream>>>(counts, offsets, cursors, aux, out + (size_t)NTOK * DM);
  k_build<<<NTOK / 256, 256, 0, stream>>>(route_e, route_w, cursors, tok, wgt);
  for (int c = 0; c < NC; c++) {
    k_ffn1<<<dim3(Fc / 512, 2048, NE), 256, 0, stream>>>(
        xb, w1t, b1, counts, offsets, tok, h, Fc, c * Fc);
    k_ffn2<<<dim3(1, 2048, NE), 256, 0, stream>>>(
        h, w2t, b2, counts, offsets, tok, wgt, out, Fc, c * Fc);
  }
}

// Round 6
// 1491.689 us; speedup vs baseline: 1.1240x; 1.1240x over previous
//
#include <hip/hip_runtime.h>
#include <hip/hip_fp16.h>
#include <cstdint>
#include <cstddef>

// MoE FFN, D=512 F=2048 E=8 K=2, N=32768 tokens. Fully fused fp16 MFMA kernel:
// per 32-token expert tile, GEMM1(+GELU) and GEMM2 interleaved over 16 F-chunks,
// h lives only in LDS. Per-slot y buffer + combine kernel (no atomics).
#define NTOK 32768
#define DM 512
#define FF 2048
#define NE 8

typedef _Float16 half8 __attribute__((ext_vector_type(8)));
typedef float floatx4 __attribute__((ext_vector_type(4)));

__device__ __forceinline__ float gelu_tanh(float v) {
  float u = v * 0.7978845608028654f * (1.f + 0.044715f * v * v);
  float ex = __expf(2.f * u);
  float t = 1.f - 2.f / (ex + 1.f);
  return 0.5f * v * (1.f + t);
}

// ---------------- transpose + fp32->fp16 cast: W (E,R,C) -> Wt (E,C,R) ----------------
__global__ __launch_bounds__(256) void k_transpose(const float* __restrict__ W,
                                                   _Float16* __restrict__ Wt, int R, int C) {
  __shared__ float tile[32][33];
  int e = blockIdx.z;
  int c0 = blockIdx.x * 32, r0 = blockIdx.y * 32;
  const float* Wp = W + (size_t)e * R * C;
  _Float16* Wtp = Wt + (size_t)e * R * C;
  int tx = threadIdx.x & 31, ty = threadIdx.x >> 5;
  #pragma unroll
  for (int rr = ty; rr < 32; rr += 8)
    tile[rr][tx] = Wp[(size_t)(r0 + rr) * C + c0 + tx];
  __syncthreads();
  #pragma unroll
  for (int cc = ty; cc < 32; cc += 8)
    Wtp[(size_t)(c0 + cc) * R + r0 + tx] = (_Float16)tile[tx][cc];
}

// ---------------- router ----------------
__global__ __launch_bounds__(256) void k_router(
    const float* __restrict__ x, const float* __restrict__ rw,
    _Float16* __restrict__ xb, int* __restrict__ route_e, float* __restrict__ route_w,
    int* __restrict__ counts, float* __restrict__ aux_acc) {
  __shared__ float s_p[NE];
  __shared__ float s_c[NE];
  __shared__ int s_cnt[NE];
  int tid = threadIdx.x, lane = tid & 63, wave = tid >> 6;
  if (tid < NE) { s_p[tid] = 0.f; s_c[tid] = 0.f; s_cnt[tid] = 0; }
  __syncthreads();
  int n = blockIdx.x * 4 + wave;
  const float4* xr = (const float4*)(x + (size_t)n * DM + lane * 8);
  float4 x0 = xr[0], x1 = xr[1];
  float xv[8] = {x0.x, x0.y, x0.z, x0.w, x1.x, x1.y, x1.z, x1.w};
  float acc[NE];
  #pragma unroll
  for (int e = 0; e < NE; e++) acc[e] = 0.f;
  const float4* rwv = (const float4*)rw;
  #pragma unroll
  for (int j = 0; j < 8; j++) {
    int d = lane * 8 + j;
    float4 r0 = rwv[d * 2], r1 = rwv[d * 2 + 1];
    float xd = xv[j];
    acc[0] += xd * r0.x; acc[1] += xd * r0.y; acc[2] += xd * r0.z; acc[3] += xd * r0.w;
    acc[4] += xd * r1.x; acc[5] += xd * r1.y; acc[6] += xd * r1.z; acc[7] += xd * r1.w;
  }
  half8 hv;
  #pragma unroll
  for (int j = 0; j < 8; j++) hv[j] = (_Float16)xv[j];
  *(half8*)(xb + (size_t)n * DM + lane * 8) = hv;
  #pragma unroll
  for (int e = 0; e < NE; e++) {
    #pragma unroll
    for (int m = 1; m < 64; m <<= 1) acc[e] += __shfl_xor(acc[e], m);
  }
  if (lane == 0) {
    int e0 = 0; float v0 = acc[0];
    for (int e = 1; e < NE; e++) if (acc[e] > v0) { v0 = acc[e]; e0 = e; }
    int e1 = (e0 == 0) ? 1 : 0; float v1 = acc[e1];
    for (int e = 0; e < NE; e++) if (e != e0 && acc[e] > v1) { v1 = acc[e]; e1 = e; }
    float w0 = 1.f / (1.f + expf(v1 - v0));
    float w1 = 1.f - w0;
    route_e[n] = e0 | (e1 << 8);
    route_w[2 * n] = w0; route_w[2 * n + 1] = w1;
    float mx = acc[0];
    for (int e = 1; e < NE; e++) mx = fmaxf(mx, acc[e]);
    float p[NE]; float s = 0.f;
    for (int e = 0; e < NE; e++) { p[e] = expf(acc[e] - mx); s += p[e]; }
    float inv = 1.f / s;
    atomicAdd(&s_cnt[e0], 1); atomicAdd(&s_cnt[e1], 1);
    for (int e = 0; e < NE; e++) atomicAdd(&s_p[e], p[e] * inv);
    atomicAdd(&s_c[e0], 1.f);
  }
  __syncthreads();
  if (tid < NE) {
    atomicAdd(&counts[tid], s_cnt[tid]);
    atomicAdd(&aux_acc[tid], s_p[tid]);
    atomicAdd(&aux_acc[NE + tid], s_c[tid]);
  }
}

// ---------------- offsets + aux ----------------
__global__ void k_finalize(const int* __restrict__ counts, int* __restrict__ offsets,
                           int* __restrict__ cursors, const float* __restrict__ aux_acc,
                           float* __restrict__ out_aux) {
  if (threadIdx.x == 0 && blockIdx.x == 0) {
    int off = 0;
    for (int e = 0; e < NE; e++) { offsets[e] = off; cursors[e] = off; off += counts[e]; }
    const float invN = 1.f / (float)NTOK;
    float aux = 0.f;
    for (int e = 0; e < NE; e++) aux += (aux_acc[e] * invN) * (aux_acc[NE + e] * invN);
    out_aux[0] = 0.01f * (float)NE * aux;
  }
}

// ---------------- compaction (also records each token's 2 slots) ----------------
__global__ __launch_bounds__(256) void k_build(
    const int* __restrict__ route_e, const float* __restrict__ route_w,
    int* __restrict__ cursors, int* __restrict__ tok, float* __restrict__ wgt,
    int* __restrict__ slotp) {
  __shared__ int s_cnt[NE];
  __shared__ int s_base[NE];
  int tid = threadIdx.x;
  if (tid < NE) s_cnt[tid] = 0;
  __syncthreads();
  int n = blockIdx.x * 256 + tid;
  int re = route_e[n];
  int e0 = re & 0xff, e1 = (re >> 8) & 0xff;
  float w0 = route_w[2 * n], w1 = route_w[2 * n + 1];
  int p0 = atomicAdd(&s_cnt[e0], 1);
  int p1 = atomicAdd(&s_cnt[e1], 1);
  __syncthreads();
  if (tid < NE) s_base[tid] = atomicAdd(&cursors[tid], s_cnt[tid]);
  __syncthreads();
  int g0 = s_base[e0] + p0, g1 = s_base[e1] + p1;
  tok[g0] = n; wgt[g0] = w0;
  tok[g1] = n; wgt[g1] = w1;
  slotp[2 * n] = g0; slotp[2 * n + 1] = g1;
}

#define MFMA16(a, b, c) __builtin_amdgcn_mfma_f32_16x16x32_f16(a, b, c, 0, 0, 0)

// ---------------- fused FFN: per 32-token expert tile ----------------
// grid (x=NE, y=1024): blockIdx.x fastest-varying -> expert e pinned to XCD e
// (4 MB L2 holds that expert's w1+w2 exactly).
__global__ __launch_bounds__(256, 2) void k_fused(
    const _Float16* __restrict__ xb, const _Float16* __restrict__ w1t,
    const _Float16* __restrict__ w2t, const float* __restrict__ b1,
    const float* __restrict__ b2, const int* __restrict__ counts,
    const int* __restrict__ offsets, const int* __restrict__ tok,
    const float* __restrict__ wgt, _Float16* __restrict__ y) {
  int e = blockIdx.x;
  int cnt = counts[e];
  int t = blockIdx.y;
  if (t * 32 >= cnt) return;
  int off = offsets[e];
  __shared__ _Float16 As[32 * 520];       // 32 rows x 512 k, row stride 520 (2-way-free banks)
  __shared__ _Float16 Hs[2][32 * 136];    // double-buffered h chunk: 32 rows x 128 F
  int tid = threadIdx.x, lane = tid & 63, wave = tid >> 6;
  int fr = lane & 15, q = lane >> 4, kf8 = q * 8;

  // ---- stage A once: 32 gathered token rows x 512 ----
  {
    int r = tid >> 3, part = tid & 7;
    int row = t * 32 + r; if (row >= cnt) row = cnt - 1;
    const _Float16* src = xb + (size_t)tok[off + row] * DM;
    #pragma unroll
    for (int i = 0; i < 8; i++) {
      int col = part * 8 + i * 64;
      *(half8*)(As + r * 520 + col) = *(const half8*)(src + col);
    }
  }
  const _Float16* w1e = w1t + (size_t)e * FF * DM;   // (F, D) k-contiguous
  const _Float16* w2e = w2t + (size_t)e * DM * FF;   // (D, F) k-contiguous
  const _Float16* b2p[8];
  #pragma unroll
  for (int cf = 0; cf < 8; cf++)
    b2p[cf] = w2e + (size_t)(wave * 128 + cf * 16 + fr) * FF + kf8;

  floatx4 acc2[2][8];
  floatx4 zero = {0.f, 0.f, 0.f, 0.f};
  #pragma unroll
  for (int m = 0; m < 2; m++)
    #pragma unroll
    for (int cf = 0; cf < 8; cf++) acc2[m][cf] = zero;

  __syncthreads();

  for (int c = 0; c < 16; c++) {
    int fc = c * 128;
    int buf = c & 1;
    // ---- GEMM1: this wave's 32 F-cols of the chunk ----
    floatx4 acc1[2][2];
    acc1[0][0] = zero; acc1[0][1] = zero; acc1[1][0] = zero; acc1[1][1] = zero;
    const _Float16* p0 = w1e + (size_t)(fc + wave * 32 + fr) * DM + kf8;
    const _Float16* p1 = p0 + (size_t)16 * DM;
    #pragma unroll
    for (int kb = 0; kb < 16; kb++) {
      half8 av0 = *(const half8*)(As + fr * 520 + kb * 32 + kf8);
      half8 av1 = *(const half8*)(As + (16 + fr) * 520 + kb * 32 + kf8);
      half8 bv0 = *(const half8*)(p0 + kb * 32);
      half8 bv1 = *(const half8*)(p1 + kb * 32);
      acc1[0][0] = MFMA16(av0, bv0, acc1[0][0]);
      acc1[1][0] = MFMA16(av1, bv0, acc1[1][0]);
      acc1[0][1] = MFMA16(av0, bv1, acc1[0][1]);
      acc1[1][1] = MFMA16(av1, bv1, acc1[1][1]);
    }
    // ---- bias + GELU -> Hs[buf] (wave-private 32-col stripe; C layout col=lane&15,row=q*4+r)
    #pragma unroll
    for (int cf = 0; cf < 2; cf++) {
      float bb = b1[e * FF + fc + wave * 32 + cf * 16 + fr];
      #pragma unroll
      for (int m = 0; m < 2; m++) {
        #pragma unroll
        for (int r = 0; r < 4; r++) {
          float v = acc1[m][cf][r] + bb;
          v = gelu_tanh(v);
          Hs[buf][(m * 16 + q * 4 + r) * 136 + wave * 32 + cf * 16 + fr] = (_Float16)v;
        }
      }
    }
    __syncthreads();
    // ---- GEMM2: accumulate this 128-wide F-slice into persistent acc2 ----
    #pragma unroll
    for (int k2 = 0; k2 < 4; k2++) {
      half8 a20 = *(const half8*)(&Hs[buf][fr * 136 + k2 * 32 + kf8]);
      half8 a21 = *(const half8*)(&Hs[buf][(16 + fr) * 136 + k2 * 32 + kf8]);
      #pragma unroll
      for (int cf = 0; cf < 8; cf++) {
        half8 bv = *(const half8*)(b2p[cf] + fc + k2 * 32);
        acc2[0][cf] = MFMA16(a20, bv, acc2[0][cf]);
        acc2[1][cf] = MFMA16(a21, bv, acc2[1][cf]);
      }
    }
  }

  // ---- epilogue: y[slot] = (acc2 + b2) * wgt, per-slot (no atomics) ----
  #pragma unroll
  for (int m = 0; m < 2; m++) {
    float wv[4]; int rowg[4]; bool ok[4];
    #pragma unroll
    for (int r = 0; r < 4; r++) {
      int trow = t * 32 + m * 16 + q * 4 + r;
      ok[r] = trow < cnt;
      rowg[r] = off + (ok[r] ? trow : 0);
      wv[r] = wgt[rowg[r]];
    }
    #pragma unroll
    for (int cf = 0; cf < 8; cf++) {
      int col = wave * 128 + cf * 16 + fr;
      float bb = b2[e * DM + col];
      #pragma unroll
      for (int r = 0; r < 4; r++)
        if (ok[r]) y[(size_t)rowg[r] * DM + col] = (_Float16)((acc2[m][cf][r] + bb) * wv[r]);
    }
  }
}

// ---------------- combine: out[n] = y[slot0[n]] + y[slot1[n]] ----------------
__global__ __launch_bounds__(256) void k_combine(const _Float16* __restrict__ y,
                                                 const int* __restrict__ slotp,
                                                 float* __restrict__ out) {
  int idx = blockIdx.x * 256 + threadIdx.x;  // one thread per 8 elements
  int n = idx >> 6;                          // DM/8 = 64 chunks per token
  int cp = (idx & 63) * 8;
  int s0 = slotp[2 * n], s1 = slotp[2 * n + 1];
  half8 a = *(const half8*)(y + (size_t)s0 * DM + cp);
  half8 b = *(const half8*)(y + (size_t)s1 * DM + cp);
  float4 o0, o1;
  o0.x = (float)a[0] + (float)b[0];
  o0.y = (float)a[1] + (float)b[1];
  o0.z = (float)a[2] + (float)b[2];
  o0.w = (float)a[3] + (float)b[3];
  o1.x = (float)a[4] + (float)b[4];
  o1.y = (float)a[5] + (float)b[5];
  o1.z = (float)a[6] + (float)b[6];
  o1.w = (float)a[7] + (float)b[7];
  *(float4*)(out + (size_t)n * DM + cp) = o0;
  *(float4*)(out + (size_t)n * DM + cp + 4) = o1;
}

extern "C" void kernel_launch(void* const* d_in, const int* in_sizes, int n_in,
                              void* d_out, int out_size, void* d_ws, size_t ws_size,
                              hipStream_t stream) {
  const float* x  = (const float*)d_in[0];
  const float* rw = (const float*)d_in[1];
  const float* w1 = (const float*)d_in[2];
  const float* b1 = (const float*)d_in[3];
  const float* w2 = (const float*)d_in[4];
  const float* b2 = (const float*)d_in[5];
  float* out = (float*)d_out;

  uint8_t* ws = (uint8_t*)d_ws;
  _Float16* xb  = (_Float16*)ws;  ws += (size_t)NTOK * DM * 2;       // 33.5 MB
  _Float16* w1t = (_Float16*)ws;  ws += (size_t)NE * FF * DM * 2;    // 16.8 MB
  _Float16* w2t = (_Float16*)ws;  ws += (size_t)NE * DM * FF * 2;    // 16.8 MB
  _Float16* y   = (_Float16*)ws;  ws += (size_t)2 * NTOK * DM * 2;   // 67.1 MB
  int*   tok     = (int*)ws;      ws += (size_t)2 * NTOK * 4;
  float* wgt     = (float*)ws;    ws += (size_t)2 * NTOK * 4;
  int*   slotp   = (int*)ws;      ws += (size_t)2 * NTOK * 4;
  int*   route_e = (int*)ws;      ws += (size_t)NTOK * 4;
  float* route_w = (float*)ws;    ws += (size_t)NTOK * 8;
  int*   counts  = (int*)ws;      ws += 8 * 4;
  int*   offsets = (int*)ws;      ws += 8 * 4;
  int*   cursors = (int*)ws;      ws += 8 * 4;
  float* aux     = (float*)ws;    ws += 16 * 4;

  hipMemsetAsync(counts, 0, (8 + 8 + 8 + 16) * 4, stream);  // counts..aux

  k_transpose<<<dim3(FF / 32, DM / 32, NE), 256, 0, stream>>>(w1, w1t, DM, FF);
  k_transpose<<<dim3(DM / 32, FF / 32, NE), 256, 0, stream>>>(w2, w2t, FF, DM);
  k_router<<<NTOK / 4, 256, 0, stream>>>(x, rw, xb, route_e, route_w, counts, aux);
  k_finalize<<<1, 64, 0, stream>>>(counts, offsets, cursors, aux, out + (size_t)NTOK * DM);
  k_build<<<NTOK / 256, 256, 0, stream>>>(route_e, route_w, cursors, tok, wgt, slotp);
  k_fused<<<dim3(NE, NTOK / 32, 1), 256, 0, stream>>>(
      xb, w1t, w2t, b1, b2, counts, offsets, tok, wgt, y);
  k_combine<<<(NTOK * DM / 8) / 256, 256, 0, stream>>>(y, slotp, out);
}